// Round 2
// baseline (26940.024 us; speedup 1.0000x reference)
//
#include <hip/hip_runtime.h>
#include <hip/hip_bf16.h>
#include <hip/hip_cooperative_groups.h>

namespace cg = cooperative_groups;

#define T_DIM 500
#define B_DIM 32
#define U_DIM 100
#define I_DIM 1024
#define E_DIM 512
#define M_DIM 512
#define CELL_DIM 1024
#define ODIM 512
#define NC 5000
#define G4 4096
#define KBODY 2048   // emb(512) + ctx(1024) + p(512)

typedef __attribute__((ext_vector_type(8))) short short8;
typedef __attribute__((ext_vector_type(4))) float f32x4;

__device__ __forceinline__ float bf2f(unsigned short u){
  union { unsigned int i; float f; } v; v.i = ((unsigned int)u) << 16; return v.f;
}
__device__ __forceinline__ unsigned short f2bf(float f){
  union { float f; unsigned int i; } v; v.f = f;
  unsigned int lsb = (v.i >> 16) & 1u;
  unsigned int r = v.i + 0x7fffu + lsb;
  return (unsigned short)(r >> 16);
}
__device__ __forceinline__ float fast_tanh(float x){
  float ax = fabsf(x);
  float e = __expf(2.0f * ax);
  float t = 1.0f - 2.0f / (e + 1.0f);
  return copysignf(t, x);
}
__device__ __forceinline__ float fast_sig(float x){
  return 1.0f / (1.0f + __expf(-x));
}
__device__ __forceinline__ short8 cvt8_bf(const float* p){
  float4 c0 = *reinterpret_cast<const float4*>(p);
  float4 c1 = *reinterpret_cast<const float4*>(p + 4);
  short8 a;
  a[0]=(short)f2bf(c0.x); a[1]=(short)f2bf(c0.y); a[2]=(short)f2bf(c0.z); a[3]=(short)f2bf(c0.w);
  a[4]=(short)f2bf(c1.x); a[5]=(short)f2bf(c1.y); a[6]=(short)f2bf(c1.z); a[7]=(short)f2bf(c1.w);
  return a;
}

// ---------- precompute kernels ----------

__global__ void k_cvt_bf16(const float* __restrict__ src, unsigned short* __restrict__ dst, int n4){
  int i = blockIdx.x * 256 + threadIdx.x;
  if (i >= n4) return;
  float4 v = reinterpret_cast<const float4*>(src)[i];
  ushort4 o;
  o.x = f2bf(v.x); o.y = f2bf(v.y); o.z = f2bf(v.z); o.w = f2bf(v.w);
  reinterpret_cast<ushort4*>(dst)[i] = o;
}

__global__ void k_embed_bf(const int* __restrict__ att_label, const float* __restrict__ emb_W,
                           unsigned short* __restrict__ embed_bf){
  int idx = blockIdx.x * 256 + threadIdx.x;      // U*B*E
  int e  = idx & (E_DIM - 1);
  int ub = idx >> 9;
  int b  = ub & (B_DIM - 1);
  int u  = ub >> 5;
  int label = (u == 0) ? (NC - 2) : att_label[(u - 1) * B_DIM + b];
  float val = 0.0f;
  if (label >= 0) val = emb_W[label * E_DIM + e];
  embed_bf[idx] = f2bf(val);
}

__global__ void k_bias(const float* __restrict__ rnn_mask, float* __restrict__ bias){
  int idx = blockIdx.x * 256 + threadIdx.x;
  if (idx < T_DIM * B_DIM) bias[idx] = (rnn_mask[idx] - 1.0f) * 1e10f;
}

// Wcomb[m,c] = sum_o Wp2s[m,o] * Wproj[o,c]
__global__ void k_wcomb(const float* __restrict__ Wp2s, const float* __restrict__ Wproj,
                        float* __restrict__ Wcomb){
  int idx = blockIdx.x * 256 + threadIdx.x;   // 512*1024
  int c = idx & (CELL_DIM - 1);
  int m = idx >> 10;
  float acc = 0.f;
  for (int k = 0; k < ODIM; ++k)
    acc += Wp2s[m * ODIM + k] * Wproj[k * CELL_DIM + c];
  Wcomb[idx] = acc;
}

// Wg[n, 0:1536] = Wx[n, :], Wg[n, 1536:2048] = Wp[n, :]  (bf16)
__global__ void k_pack_wg(const float* __restrict__ Wx, const float* __restrict__ Wp,
                          unsigned short* __restrict__ Wg){
  int idx4 = blockIdx.x * 256 + threadIdx.x;  // 4096*512
  int n = idx4 >> 9;
  int k = (idx4 & 511) * 4;
  float4 v = (k < 1536) ? *reinterpret_cast<const float4*>(Wx + n * 1536 + k)
                        : *reinterpret_cast<const float4*>(Wp + n * 512 + (k - 1536));
  ushort4 o; o.x = f2bf(v.x); o.y = f2bf(v.y); o.z = f2bf(v.z); o.w = f2bf(v.w);
  *reinterpret_cast<ushort4*>(Wg + n * 2048 + k) = o;
}

// Wpc[n<512] = Wproj rows; Wpc[n>=512] = Wcomb rows (bf16)
__global__ void k_pack_wpc(const float* __restrict__ Wproj, const float* __restrict__ Wcomb,
                           unsigned short* __restrict__ Wpc){
  int idx4 = blockIdx.x * 256 + threadIdx.x; // 1024*256
  int n = idx4 >> 8;
  int k = (idx4 & 255) * 4;
  const float* src = (n < 512) ? (Wproj + n * 1024 + k) : (Wcomb + (n - 512) * 1024 + k);
  float4 v = *reinterpret_cast<const float4*>(src);
  ushort4 o; o.x = f2bf(v.x); o.y = f2bf(v.y); o.z = f2bf(v.z); o.w = f2bf(v.w);
  *reinterpret_cast<ushort4*>(Wpc + n * 1024 + k) = o;
}

// att_h = data @ Wi2h^T -> bf16 [16000,512]   (validated round 1)
__global__ __launch_bounds__(256) void k_atth(const unsigned short* __restrict__ A,
                                              const unsigned short* __restrict__ Bm,
                                              unsigned short* __restrict__ C){
  const int mt = blockIdx.x % 250;
  const int nt = blockIdx.x / 250;
  const int wave = threadIdx.x >> 6;
  const int lane = threadIdx.x & 63;
  const int r16 = lane & 15;
  const int kl = (lane >> 4) * 8;
  const unsigned short* aptr = A + (mt * 64 + wave * 16 + r16) * 1024 + kl;
  const unsigned short* bptr = Bm + (nt * 64 + r16) * 1024 + kl;
  f32x4 acc0 = {0,0,0,0}, acc1 = {0,0,0,0}, acc2 = {0,0,0,0}, acc3 = {0,0,0,0};
  for (int kk = 0; kk < 1024; kk += 32) {
    short8 a  = *reinterpret_cast<const short8*>(aptr + kk);
    short8 b0 = *reinterpret_cast<const short8*>(bptr + kk);
    short8 b1 = *reinterpret_cast<const short8*>(bptr + 16 * 1024 + kk);
    short8 b2 = *reinterpret_cast<const short8*>(bptr + 32 * 1024 + kk);
    short8 b3 = *reinterpret_cast<const short8*>(bptr + 48 * 1024 + kk);
    acc0 = __builtin_amdgcn_mfma_f32_16x16x32_bf16(a, b0, acc0, 0, 0, 0);
    acc1 = __builtin_amdgcn_mfma_f32_16x16x32_bf16(a, b1, acc1, 0, 0, 0);
    acc2 = __builtin_amdgcn_mfma_f32_16x16x32_bf16(a, b2, acc2, 0, 0, 0);
    acc3 = __builtin_amdgcn_mfma_f32_16x16x32_bf16(a, b3, acc3, 0, 0, 0);
  }
  const int orow = mt * 64 + wave * 16 + (lane >> 4) * 4;
  const int ocol = nt * 64 + r16;
  #pragma unroll
  for (int r = 0; r < 4; ++r) {
    C[(orow + r) * 512 + ocol]      = f2bf(acc0[r]);
    C[(orow + r) * 512 + ocol + 16] = f2bf(acc1[r]);
    C[(orow + r) * 512 + ocol + 32] = f2bf(acc2[r]);
    C[(orow + r) * 512 + ocol + 48] = f2bf(acc3[r]);
  }
}

// ---------- persistent cooperative loop kernel ----------
// grid = 512 blocks x 256 threads, 4 grid syncs per step.
__global__ __launch_bounds__(256, 2) void k_loop(
    const unsigned short* __restrict__ data_bf,
    const unsigned short* __restrict__ atth_bf,
    const unsigned short* __restrict__ embed_bf,
    const float* __restrict__ bias,
    const unsigned short* __restrict__ Wg,
    const unsigned short* __restrict__ Wpc,
    const float* __restrict__ bvec,
    const float* __restrict__ w_v,
    const float* __restrict__ att_mask,
    float* __restrict__ c_ws,
    unsigned short* __restrict__ h_bf,
    unsigned short* __restrict__ p_bf,
    float* __restrict__ state,
    float* __restrict__ ctx,
    float* __restrict__ scal,
    float* __restrict__ out)
{
  cg::grid_group grid = cg::this_grid();
  const int bid = blockIdx.x;
  const int tid = threadIdx.x;
  const int wv = tid >> 6;
  const int lane = tid & 63;
  const int r16 = lane & 15;
  const int khi = lane >> 4;          // k-offset = khi*8

  __shared__ float s_g[4][16][16];
  __shared__ float s_s[64];

  for (int u = 0; u < U_DIM; ++u) {
    // ---------- Phase A: gates MFMA + cell (blocks 0..127); out[u-1] ctx (128..159)
    if (bid < 128) {
      const int mt = bid >> 6;        // bid and bid+64 share an XCD -> weight L2 reuse
      const int jt = bid & 63;
      const unsigned short* brow = Wg + ((size_t)(wv * 1024 + jt * 16 + r16)) * KBODY + khi * 8;
      const int arow = mt * 16 + r16;
      const unsigned short* aemb = embed_bf + ((size_t)(u * 32 + arow)) * 512 + khi * 8;
      const float* actx = ctx + arow * 1024 + khi * 8;
      const unsigned short* ap = p_bf + arow * 512 + khi * 8;
      f32x4 acc0 = {0,0,0,0}, acc1 = {0,0,0,0};
      #pragma unroll 4
      for (int ks = 0; ks < 16; ks += 2) {
        short8 a0 = *reinterpret_cast<const short8*>(aemb + ks * 32);
        short8 b0 = *reinterpret_cast<const short8*>(brow + ks * 32);
        short8 a1 = *reinterpret_cast<const short8*>(aemb + ks * 32 + 32);
        short8 b1 = *reinterpret_cast<const short8*>(brow + ks * 32 + 32);
        acc0 = __builtin_amdgcn_mfma_f32_16x16x32_bf16(a0, b0, acc0, 0, 0, 0);
        acc1 = __builtin_amdgcn_mfma_f32_16x16x32_bf16(a1, b1, acc1, 0, 0, 0);
      }
      #pragma unroll 4
      for (int ks = 0; ks < 32; ks += 2) {
        short8 a0 = cvt8_bf(actx + ks * 32);
        short8 b0 = *reinterpret_cast<const short8*>(brow + 512 + ks * 32);
        short8 a1 = cvt8_bf(actx + ks * 32 + 32);
        short8 b1 = *reinterpret_cast<const short8*>(brow + 512 + ks * 32 + 32);
        acc0 = __builtin_amdgcn_mfma_f32_16x16x32_bf16(a0, b0, acc0, 0, 0, 0);
        acc1 = __builtin_amdgcn_mfma_f32_16x16x32_bf16(a1, b1, acc1, 0, 0, 0);
      }
      #pragma unroll 4
      for (int ks = 0; ks < 16; ks += 2) {
        short8 a0 = *reinterpret_cast<const short8*>(ap + ks * 32);
        short8 b0 = *reinterpret_cast<const short8*>(brow + 1536 + ks * 32);
        short8 a1 = *reinterpret_cast<const short8*>(ap + ks * 32 + 32);
        short8 b1 = *reinterpret_cast<const short8*>(brow + 1536 + ks * 32 + 32);
        acc0 = __builtin_amdgcn_mfma_f32_16x16x32_bf16(a0, b0, acc0, 0, 0, 0);
        acc1 = __builtin_amdgcn_mfma_f32_16x16x32_bf16(a1, b1, acc1, 0, 0, 0);
      }
      const float bv = bvec[wv * 1024 + jt * 16 + r16];
      #pragma unroll
      for (int r = 0; r < 4; ++r)
        s_g[wv][khi * 4 + r][r16] = acc0[r] + acc1[r] + bv;
      __syncthreads();
      const int b_loc = tid >> 4, j_loc = tid & 15;
      float ig = fast_sig(s_g[0][b_loc][j_loc]);
      float fg = fast_sig(s_g[1][b_loc][j_loc]);
      float gg = fast_tanh(s_g[2][b_loc][j_loc]);
      float og = fast_sig(s_g[3][b_loc][j_loc]);
      const int idx = (mt * 16 + b_loc) * 1024 + jt * 16 + j_loc;
      float c = fg * c_ws[idx] + ig * gg;
      c = fminf(fmaxf(c, -1.0f), 1.0f);
      c_ws[idx] = c;
      h_bf[idx] = f2bf(og * fast_tanh(c));
      __syncthreads();
    } else if (bid >= 128 && bid < 160) {
      if (u > 0) {
        const int b = bid - 128;
        const float am = att_mask[(u - 1) * 32 + b];
        float4 v = *reinterpret_cast<const float4*>(ctx + b * 1024 + tid * 4);
        float4 o; o.x = v.x * am; o.y = v.y * am; o.z = v.z * am; o.w = v.w * am;
        *reinterpret_cast<float4*>(out + ((size_t)(u - 1) * 32 + b) * 1536 + 512 + tid * 4) = o;
      }
    }
    grid.sync();

    // ---------- Phase B: p/state MFMA (blocks 0..31); ctx zero (480..511)
    if (bid < 32) {
      const int task = bid * 4 + wv;          // 0..127
      const int mt = task & 1, nt = task >> 1; // nt 0..63
      const unsigned short* brow = Wpc + ((size_t)(nt * 16 + r16)) * 1024 + khi * 8;
      const unsigned short* arow = h_bf + ((size_t)(mt * 16 + r16)) * 1024 + khi * 8;
      f32x4 acc0 = {0,0,0,0}, acc1 = {0,0,0,0};
      #pragma unroll 4
      for (int ks = 0; ks < 32; ks += 2) {
        short8 a0 = *reinterpret_cast<const short8*>(arow + ks * 32);
        short8 b0 = *reinterpret_cast<const short8*>(brow + ks * 32);
        short8 a1 = *reinterpret_cast<const short8*>(arow + ks * 32 + 32);
        short8 b1 = *reinterpret_cast<const short8*>(brow + ks * 32 + 32);
        acc0 = __builtin_amdgcn_mfma_f32_16x16x32_bf16(a0, b0, acc0, 0, 0, 0);
        acc1 = __builtin_amdgcn_mfma_f32_16x16x32_bf16(a1, b1, acc1, 0, 0, 0);
      }
      const int n = nt * 16 + r16;
      #pragma unroll
      for (int r = 0; r < 4; ++r) {
        const int b = mt * 16 + khi * 4 + r;
        const float v = acc0[r] + acc1[r];
        if (n < 512) {
          p_bf[b * 512 + n] = f2bf(v);
          out[((size_t)u * 32 + b) * 1536 + n] = v * att_mask[u * 32 + b];
        } else {
          state[b * 512 + (n - 512)] = v;
        }
      }
    } else if (bid >= 480) {
      float4 z = {0.f, 0.f, 0.f, 0.f};
      *reinterpret_cast<float4*>(ctx + (bid - 480) * 1024 + tid * 4) = z;
    }
    grid.sync();

    // ---------- Phase C: attention scalars (all blocks)
    {
      const int wg = bid * 4 + wv;            // 0..2047
      const int m0 = lane * 8;
      for (int r = wg; r < T_DIM * B_DIM; r += 2048) {
        const int b = r & 31;
        const unsigned short* apt = atth_bf + (size_t)r * 512 + m0;
        ushort4 a0 = *reinterpret_cast<const ushort4*>(apt);
        ushort4 a1 = *reinterpret_cast<const ushort4*>(apt + 4);
        float4 s0 = *reinterpret_cast<const float4*>(state + b * 512 + m0);
        float4 s1 = *reinterpret_cast<const float4*>(state + b * 512 + m0 + 4);
        float4 w0 = *reinterpret_cast<const float4*>(w_v + m0);
        float4 w1 = *reinterpret_cast<const float4*>(w_v + m0 + 4);
        float acc = w0.x * fast_tanh(s0.x + bf2f(a0.x))
                  + w0.y * fast_tanh(s0.y + bf2f(a0.y))
                  + w0.z * fast_tanh(s0.z + bf2f(a0.z))
                  + w0.w * fast_tanh(s0.w + bf2f(a0.w))
                  + w1.x * fast_tanh(s1.x + bf2f(a1.x))
                  + w1.y * fast_tanh(s1.y + bf2f(a1.y))
                  + w1.z * fast_tanh(s1.z + bf2f(a1.z))
                  + w1.w * fast_tanh(s1.w + bf2f(a1.w));
        #pragma unroll
        for (int off = 32; off >= 1; off >>= 1)
          acc += __shfl_xor(acc, off, 64);
        if (lane == 0)
          scal[r] = fast_sig(acc + bias[r]);
      }
    }
    grid.sync();

    // ---------- Phase D: ctx = sum_t data*scal, atomic accumulate (blocks 0..319)
    if (bid < 320) {
      const int tc = bid >> 5;                // 0..9 (50 t each)
      const int b  = bid & 31;
      if (tid < 50) s_s[tid] = scal[(tc * 50 + tid) * 32 + b];
      __syncthreads();
      const int i0 = tid * 4;
      float4 acc = {0.f, 0.f, 0.f, 0.f};
      const unsigned short* dp = data_bf + ((size_t)(tc * 50 * 32 + b)) * 1024 + i0;
      #pragma unroll 5
      for (int tt = 0; tt < 50; ++tt) {
        ushort4 v = *reinterpret_cast<const ushort4*>(dp);
        const float s = s_s[tt];
        acc.x += bf2f(v.x) * s;
        acc.y += bf2f(v.y) * s;
        acc.z += bf2f(v.z) * s;
        acc.w += bf2f(v.w) * s;
        dp += 32 * 1024;
      }
      float* cp = ctx + b * 1024 + i0;
      atomicAdd(cp + 0, acc.x);
      atomicAdd(cp + 1, acc.y);
      atomicAdd(cp + 2, acc.z);
      atomicAdd(cp + 3, acc.w);
      __syncthreads();
    }
    grid.sync();
  }

  // trailing out write for u = 99 ctx
  if (bid >= 128 && bid < 160) {
    const int b = bid - 128;
    const float am = att_mask[99 * 32 + b];
    float4 v = *reinterpret_cast<const float4*>(ctx + b * 1024 + tid * 4);
    float4 o; o.x = v.x * am; o.y = v.y * am; o.z = v.z * am; o.w = v.w * am;
    *reinterpret_cast<float4*>(out + ((size_t)99 * 32 + b) * 1536 + 512 + tid * 4) = o;
  }
}

extern "C" void kernel_launch(void* const* d_in, const int* in_sizes, int n_in,
                              void* d_out, int out_size, void* d_ws, size_t ws_size,
                              hipStream_t stream) {
  const float* data     = (const float*)d_in[0];
  const float* att_mask = (const float*)d_in[1];
  const int*   att_label= (const int*)d_in[2];
  const float* rnn_mask = (const float*)d_in[3];
  const float* emb_W    = (const float*)d_in[4];
  const float* Wi2h     = (const float*)d_in[5];
  const float* Wp2s     = (const float*)d_in[6];
  const float* w_att_v  = (const float*)d_in[7];
  const float* Wx       = (const float*)d_in[8];
  const float* Wp       = (const float*)d_in[9];
  const float* bvec     = (const float*)d_in[10];
  const float* Wproj    = (const float*)d_in[11];
  float* out = (float*)d_out;

  char* ws = (char*)d_ws;
  size_t off = 0;
  auto alloc = [&](size_t bytes){ void* p = ws + off; off += (bytes + 255) & ~(size_t)255; return p; };
  unsigned short* data_bf = (unsigned short*)alloc((size_t)T_DIM * B_DIM * I_DIM * 2);
  unsigned short* atth_bf = (unsigned short*)alloc((size_t)T_DIM * B_DIM * M_DIM * 2);
  unsigned short* Wi2h_bf = (unsigned short*)alloc((size_t)M_DIM * I_DIM * 2);
  unsigned short* embed_bf= (unsigned short*)alloc((size_t)U_DIM * B_DIM * E_DIM * 2);
  unsigned short* Wg_bf   = (unsigned short*)alloc((size_t)G4 * KBODY * 2);
  unsigned short* Wpc_bf  = (unsigned short*)alloc((size_t)1024 * 1024 * 2);
  float* bias     = (float*)alloc((size_t)T_DIM * B_DIM * 4);
  float* Wcomb    = (float*)alloc((size_t)M_DIM * CELL_DIM * 4);
  float* c_ws     = (float*)alloc((size_t)B_DIM * CELL_DIM * 4);
  float* state_ws = (float*)alloc((size_t)B_DIM * M_DIM * 4);
  float* ctx_ws   = (float*)alloc((size_t)B_DIM * I_DIM * 4);
  float* scal     = (float*)alloc((size_t)T_DIM * B_DIM * 4);
  unsigned short* h_bf = (unsigned short*)alloc((size_t)B_DIM * CELL_DIM * 2);
  unsigned short* p_bf = (unsigned short*)alloc((size_t)B_DIM * ODIM * 2);

  hipMemsetAsync(c_ws, 0, (size_t)B_DIM * CELL_DIM * 4, stream);
  hipMemsetAsync(ctx_ws, 0, (size_t)B_DIM * I_DIM * 4, stream);
  hipMemsetAsync(p_bf, 0, (size_t)B_DIM * ODIM * 2, stream);

  k_cvt_bf16<<<(T_DIM * B_DIM * I_DIM / 4 + 255) / 256, 256, 0, stream>>>(data, data_bf, T_DIM * B_DIM * I_DIM / 4);
  k_cvt_bf16<<<(M_DIM * I_DIM / 4 + 255) / 256, 256, 0, stream>>>(Wi2h, Wi2h_bf, M_DIM * I_DIM / 4);
  k_atth<<<2000, 256, 0, stream>>>(data_bf, Wi2h_bf, atth_bf);
  k_embed_bf<<<U_DIM * B_DIM * E_DIM / 256, 256, 0, stream>>>(att_label, emb_W, embed_bf);
  k_bias<<<(T_DIM * B_DIM + 255) / 256, 256, 0, stream>>>(rnn_mask, bias);
  k_wcomb<<<M_DIM * CELL_DIM / 256, 256, 0, stream>>>(Wp2s, Wproj, Wcomb);
  k_pack_wg<<<G4 * (KBODY / 4) / 256, 256, 0, stream>>>(Wx, Wp, Wg_bf);
  k_pack_wpc<<<1024 * 256 / 256, 256, 0, stream>>>(Wproj, Wcomb, Wpc_bf);

  void* args[] = {
    (void*)&data_bf, (void*)&atth_bf, (void*)&embed_bf, (void*)&bias,
    (void*)&Wg_bf, (void*)&Wpc_bf, (void*)&bvec, (void*)&w_att_v, (void*)&att_mask,
    (void*)&c_ws, (void*)&h_bf, (void*)&p_bf, (void*)&state_ws, (void*)&ctx_ws,
    (void*)&scal, (void*)&out
  };
  hipLaunchCooperativeKernel((const void*)k_loop, dim3(512), dim3(256), args, 0, stream);
}